// Round 3
// baseline (415.306 us; speedup 1.0000x reference)
//
#include <hip/hip_runtime.h>
#include <hip/hip_bf16.h>

// SiLU forward: out = x * sigmoid(x) = x / (1 + exp(-x))
// Input: float32, 4*4096*4096 = 67,108,864 elements.
// Memory-bound streaming op. R1 analysis: kernel portion ~118us (4.6 TB/s).
// This version: 4x float4 per thread (4 outstanding loads for MLP),
// nontemporal load/store (touch-once data, 512MB > L3, skip write-allocate),
// v_rcp_f32 instead of full-precision divide sequence.
// R2 fix: nontemporal builtins need a NATIVE vector type, not HIP_vector_type.

typedef float f32x4 __attribute__((ext_vector_type(4)));

__global__ __launch_bounds__(256) void silu_f32x4x4_kernel(const f32x4* __restrict__ x,
                                                           f32x4* __restrict__ out,
                                                           int n4) {
    // Each block covers 256 threads * 4 float4; consecutive lanes access
    // consecutive float4s within each of the 4 coalesced load instructions.
    int base = blockIdx.x * (256 * 4) + threadIdx.x;

    f32x4 v[4];
#pragma unroll
    for (int k = 0; k < 4; ++k) {
        int idx = base + k * 256;
        if (idx < n4) v[k] = __builtin_nontemporal_load(&x[idx]);
    }

#pragma unroll
    for (int k = 0; k < 4; ++k) {
        int idx = base + k * 256;
        if (idx < n4) {
            f32x4 s = v[k];
            f32x4 r;
            r.x = s.x * __builtin_amdgcn_rcpf(1.0f + __expf(-s.x));
            r.y = s.y * __builtin_amdgcn_rcpf(1.0f + __expf(-s.y));
            r.z = s.z * __builtin_amdgcn_rcpf(1.0f + __expf(-s.z));
            r.w = s.w * __builtin_amdgcn_rcpf(1.0f + __expf(-s.w));
            __builtin_nontemporal_store(r, &out[idx]);
        }
    }
}

extern "C" void kernel_launch(void* const* d_in, const int* in_sizes, int n_in,
                              void* d_out, int out_size, void* d_ws, size_t ws_size,
                              hipStream_t stream) {
    const float* x = (const float*)d_in[0];
    float* out = (float*)d_out;
    int n = in_sizes[0];            // 67,108,864
    int n4 = n / 4;                 // 16,777,216 float4s

    const int block = 256;
    const int per_block = block * 4;                  // 1024 float4s per block
    int grid = (n4 + per_block - 1) / per_block;      // 16,384 blocks

    silu_f32x4x4_kernel<<<grid, block, 0, stream>>>(
        (const f32x4*)x, (f32x4*)out, n4);
}